// Round 1
// baseline (2724.312 us; speedup 1.0000x reference)
//
#include <hip/hip_runtime.h>

typedef _Float16 f16;
typedef _Float16 f16x2 __attribute__((ext_vector_type(2)));
typedef _Float16 f16x8 __attribute__((ext_vector_type(8)));
typedef float    f32x4 __attribute__((ext_vector_type(4)));

__device__ __forceinline__ f16x2 as_h2(unsigned int u) {
  union { unsigned int u; f16x2 h; } c; c.u = u; return c.h;
}
__device__ __forceinline__ unsigned int pack2(float x, float y) {
  union { f16x2 h; unsigned int u; } c; c.h = f16x2{(f16)x, (f16)y}; return c.u;
}
__device__ __forceinline__ float dot2f(unsigned int w, unsigned int h, float acc) {
#if __has_builtin(__builtin_amdgcn_fdot2)
  return __builtin_amdgcn_fdot2(as_h2(w), as_h2(h), acc, false);
#else
  f16x2 a = as_h2(w), b = as_h2(h);
  return acc + (float)a.x * (float)b.x + (float)a.y * (float)b.y;
#endif
}
__device__ __forceinline__ float sigmoidf_(float x) { return 1.f / (1.f + __expf(-x)); }
__device__ __forceinline__ float tanhf_(float x) { float e = __expf(2.f * x); return 1.f - 2.f / (e + 1.f); }

#define GLDS(gsrc, ldst) __builtin_amdgcn_global_load_lds( \
    (const __attribute__((address_space(1))) void*)(gsrc), \
    (__attribute__((address_space(3))) void*)(ldst), 16, 0, 0)

// ---------------- fp32 -> fp16 conversion ----------------
__global__ void cvt_f32_f16(const float* __restrict__ in, f16* __restrict__ out, long n) {
  long i = ((long)blockIdx.x * blockDim.x + threadIdx.x) * 8;
  long stride = (long)gridDim.x * blockDim.x * 8;
  for (; i < n; i += stride) {
    float4 a = *(const float4*)(in + i);
    float4 b = *(const float4*)(in + i + 4);
    f16x8 h = {(f16)a.x, (f16)a.y, (f16)a.z, (f16)a.w,
               (f16)b.x, (f16)b.y, (f16)b.z, (f16)b.w};
    *(f16x8*)(out + i) = h;
  }
}

// ---------------- MFMA GEMM: out[M,N] = A[M,K] @ W[N,K]^T + bias1[N]+bias2[N] ----------------
// M = 32768 fixed by grid, 128x128 tile, BK=32, 4 waves (2x2), 16x16x32 f16 MFMA.
template<int K>
__global__ __launch_bounds__(256) void gemm_bias(const f16* __restrict__ A,
                                                 const f16* __restrict__ W,
                                                 const float* __restrict__ bias1,
                                                 const float* __restrict__ bias2,
                                                 float* __restrict__ out, int N) {
  constexpr int BK = 32;
  __shared__ f16 As[2][128 * BK];
  __shared__ f16 Bs[2][128 * BK];
  const int tid = threadIdx.x;
  const int wid = tid >> 6, lane = tid & 63;
  const int m0 = blockIdx.x * 128, n0 = blockIdx.y * 128;
  const int wr = (wid >> 1) * 64, wc = (wid & 1) * 64;
  const int r = lane & 15, kg = lane >> 4;

  f32x4 acc[4][4];
  #pragma unroll
  for (int i = 0; i < 4; ++i)
    #pragma unroll
    for (int j = 0; j < 4; ++j) acc[i][j] = f32x4{0.f, 0.f, 0.f, 0.f};

  auto stage = [&](int buf, int k0) {
    #pragma unroll
    for (int i = 0; i < 2; ++i) {
      int c = tid + 256 * i;                       // chunk: 16B = 8 halves
      const f16* asrc = A + (long)(m0 + (c >> 2)) * K + k0 + (c & 3) * 8;
      GLDS(asrc, &As[buf][(64 * wid + 256 * i) * 8]);
      const f16* wsrc = W + (long)(n0 + (c >> 2)) * K + k0 + (c & 3) * 8;
      GLDS(wsrc, &Bs[buf][(64 * wid + 256 * i) * 8]);
    }
  };

  stage(0, 0);
  for (int kt = 0; kt < K / BK; ++kt) {
    __syncthreads();                               // staged tile ready; prior reads done
    if (kt + 1 < K / BK) stage((kt + 1) & 1, (kt + 1) * BK);
    const f16* Ab = As[kt & 1];
    const f16* Bb = Bs[kt & 1];
    f16x8 af[4], bf[4];
    #pragma unroll
    for (int f = 0; f < 4; ++f) {
      af[f] = *(const f16x8*)&Ab[(wr + f * 16 + r) * BK + kg * 8];
      bf[f] = *(const f16x8*)&Bb[(wc + f * 16 + r) * BK + kg * 8];
    }
    #pragma unroll
    for (int mf = 0; mf < 4; ++mf)
      #pragma unroll
      for (int nf = 0; nf < 4; ++nf)
        acc[mf][nf] = __builtin_amdgcn_mfma_f32_16x16x32_f16(af[mf], bf[nf], acc[mf][nf], 0, 0, 0);
  }

  #pragma unroll
  for (int nf = 0; nf < 4; ++nf) {
    int n = n0 + wc + nf * 16 + r;
    float bsum = bias1[n] + bias2[n];
    #pragma unroll
    for (int mf = 0; mf < 4; ++mf) {
      #pragma unroll
      for (int q = 0; q < 4; ++q) {
        int m = m0 + wr + mf * 16 + kg * 4 + q;
        out[(long)m * N + n] = acc[mf][nf][q] + bsum;
      }
    }
  }
}

// ---------------- LSTM layer 1: H=256, gates=1024. Whh in VGPRs (k<192) + LDS (k>=192) ----------------
__global__ __launch_bounds__(512) void lstm_l1(const float* __restrict__ xg,   // (64,512,1024) f32
                                               const float* __restrict__ Whh,  // (1024,256) f32
                                               f16* __restrict__ hout) {       // (64,512,256) f16
  __shared__ uint2 wtail[16][1024];   // 128 KB: unit u covers k=192+4u..+3 for gate g
  __shared__ uint4 hbuf[32];          // 256 halves of h
  __shared__ float gact[1024];
  const int b = blockIdx.x;
  const int t = threadIdx.x;
  const int g0 = t, g1 = t + 512;

  unsigned int w0[96], w1[96];        // pairs (2p,2p+1), k<192
  #pragma unroll
  for (int p = 0; p < 96; ++p) {
    float2 f0 = *(const float2*)&Whh[g0 * 256 + 2 * p];
    float2 f1 = *(const float2*)&Whh[g1 * 256 + 2 * p];
    w0[p] = pack2(f0.x, f0.y);
    w1[p] = pack2(f1.x, f1.y);
  }
  #pragma unroll
  for (int u = 0; u < 16; ++u) {
    float4 f0 = *(const float4*)&Whh[g0 * 256 + 192 + 4 * u];
    wtail[u][g0] = make_uint2(pack2(f0.x, f0.y), pack2(f0.z, f0.w));
    float4 f1 = *(const float4*)&Whh[g1 * 256 + 192 + 4 * u];
    wtail[u][g1] = make_uint2(pack2(f1.x, f1.y), pack2(f1.z, f1.w));
  }
  if (t < 32) hbuf[t] = make_uint4(0, 0, 0, 0);
  float c = 0.f;                      // valid for t<256
  __syncthreads();

  const bool g1_sig = (t >= 256);     // g1 in [512,768) -> tanh, [768,1024) -> sigmoid
  for (int ts = 0; ts < 512; ++ts) {
    const long base = ((long)b * 512 + ts);
    float a0 = xg[base * 1024 + g0];
    float a1 = xg[base * 1024 + g1];
    #pragma unroll
    for (int i = 0; i < 24; ++i) {
      uint4 hv = hbuf[i];
      a0 = dot2f(w0[4 * i + 0], hv.x, a0); a0 = dot2f(w0[4 * i + 1], hv.y, a0);
      a0 = dot2f(w0[4 * i + 2], hv.z, a0); a0 = dot2f(w0[4 * i + 3], hv.w, a0);
      a1 = dot2f(w1[4 * i + 0], hv.x, a1); a1 = dot2f(w1[4 * i + 1], hv.y, a1);
      a1 = dot2f(w1[4 * i + 2], hv.z, a1); a1 = dot2f(w1[4 * i + 3], hv.w, a1);
    }
    #pragma unroll
    for (int i = 0; i < 8; ++i) {
      uint4 hv = hbuf[24 + i];
      uint2 wa0 = wtail[2 * i][g0], wb0 = wtail[2 * i + 1][g0];
      uint2 wa1 = wtail[2 * i][g1], wb1 = wtail[2 * i + 1][g1];
      a0 = dot2f(wa0.x, hv.x, a0); a0 = dot2f(wa0.y, hv.y, a0);
      a0 = dot2f(wb0.x, hv.z, a0); a0 = dot2f(wb0.y, hv.w, a0);
      a1 = dot2f(wa1.x, hv.x, a1); a1 = dot2f(wa1.y, hv.y, a1);
      a1 = dot2f(wb1.x, hv.z, a1); a1 = dot2f(wb1.y, hv.w, a1);
    }
    gact[g0] = sigmoidf_(a0);                       // g0 in [0,512): i or f -> sigmoid
    gact[g1] = g1_sig ? sigmoidf_(a1) : tanhf_(a1);
    __syncthreads();
    if (t < 256) {
      float i_ = gact[t], f_ = gact[256 + t], gg = gact[512 + t], o_ = gact[768 + t];
      c = f_ * c + i_ * gg;
      float hn = o_ * tanhf_(c);
      reinterpret_cast<f16*>(hbuf)[t] = (f16)hn;
      hout[base * 256 + t] = (f16)hn;
    }
    __syncthreads();
  }
}

// ---------------- LSTM layer 2: H=128, gates=512. Whh fully in LDS ----------------
__global__ __launch_bounds__(512) void lstm_l2(const float* __restrict__ xg,   // (64,512,512) f32
                                               const float* __restrict__ Whh,  // (512,128) f32
                                               f16* __restrict__ hout) {       // (64,512,128) f16
  __shared__ uint2 wlds[32][512];     // 128 KB: unit u covers k=4u..+3
  __shared__ uint4 hbuf[16];          // 128 halves
  __shared__ float gact[512];
  const int b = blockIdx.x, t = threadIdx.x;
  #pragma unroll
  for (int u = 0; u < 32; ++u) {
    float4 f = *(const float4*)&Whh[t * 128 + 4 * u];
    wlds[u][t] = make_uint2(pack2(f.x, f.y), pack2(f.z, f.w));
  }
  if (t < 16) hbuf[t] = make_uint4(0, 0, 0, 0);
  float c = 0.f;
  __syncthreads();
  const int type = t >> 7;            // 0:i 1:f 2:g 3:o
  for (int ts = 0; ts < 512; ++ts) {
    const long base = ((long)b * 512 + ts);
    float a = xg[base * 512 + t];
    #pragma unroll
    for (int i = 0; i < 16; ++i) {
      uint4 hv = hbuf[i];
      uint2 wa = wlds[2 * i][t], wb = wlds[2 * i + 1][t];
      a = dot2f(wa.x, hv.x, a); a = dot2f(wa.y, hv.y, a);
      a = dot2f(wb.x, hv.z, a); a = dot2f(wb.y, hv.w, a);
    }
    gact[t] = (type == 2) ? tanhf_(a) : sigmoidf_(a);
    __syncthreads();
    if (t < 128) {
      float i_ = gact[t], f_ = gact[128 + t], gg = gact[256 + t], o_ = gact[384 + t];
      c = f_ * c + i_ * gg;
      float hn = o_ * tanhf_(c);
      reinterpret_cast<f16*>(hbuf)[t] = (f16)hn;
      hout[base * 128 + t] = (f16)hn;
    }
    __syncthreads();
  }
}

// ---------------- LSTM layer 3: H=64, gates=256. Only final h needed ----------------
__global__ __launch_bounds__(256) void lstm_l3(const float* __restrict__ xg,    // (64,512,256) f32
                                               const float* __restrict__ Whh,   // (256,64) f32
                                               float* __restrict__ h3last) {    // (64,64) f32
  __shared__ uint2 wlds[16][256];     // 32 KB
  __shared__ uint4 hbuf[8];           // 64 halves
  __shared__ float gact[256];
  const int b = blockIdx.x, t = threadIdx.x;
  #pragma unroll
  for (int u = 0; u < 16; ++u) {
    float4 f = *(const float4*)&Whh[t * 64 + 4 * u];
    wlds[u][t] = make_uint2(pack2(f.x, f.y), pack2(f.z, f.w));
  }
  if (t < 8) hbuf[t] = make_uint4(0, 0, 0, 0);
  float c = 0.f;
  __syncthreads();
  const int type = t >> 6;
  for (int ts = 0; ts < 512; ++ts) {
    float a = xg[((long)b * 512 + ts) * 256 + t];
    #pragma unroll
    for (int i = 0; i < 8; ++i) {
      uint4 hv = hbuf[i];
      uint2 wa = wlds[2 * i][t], wb = wlds[2 * i + 1][t];
      a = dot2f(wa.x, hv.x, a); a = dot2f(wa.y, hv.y, a);
      a = dot2f(wb.x, hv.z, a); a = dot2f(wb.y, hv.w, a);
    }
    gact[t] = (type == 2) ? tanhf_(a) : sigmoidf_(a);
    __syncthreads();
    if (t < 64) {
      float i_ = gact[t], f_ = gact[64 + t], gg = gact[128 + t], o_ = gact[192 + t];
      c = f_ * c + i_ * gg;
      float hn = o_ * tanhf_(c);
      reinterpret_cast<f16*>(hbuf)[t] = (f16)hn;
      if (ts == 511) h3last[b * 64 + t] = hn;
    }
    __syncthreads();
  }
}

// ---------------- head: deep/wide + final linear ----------------
__global__ __launch_bounds__(256) void head_kernel(const float* __restrict__ x,       // (64,512,2048)
                                                   const float* __restrict__ h3last,  // (64,64)
                                                   const float* __restrict__ Wd, const float* __restrict__ bd,
                                                   const float* __restrict__ Ww, const float* __restrict__ bw,
                                                   const float* __restrict__ Wo, const float* __restrict__ bo,
                                                   float* __restrict__ outp) {
  __shared__ float part[256];
  __shared__ float comb[64];
  const int b = blockIdx.x, t = threadIdx.x;
  const int o = t & 31, seg = t >> 5;
  const float* xl = x + ((long)b * 512 + 511) * 2048;
  float s = 0.f;
  for (int k = seg * 256; k < seg * 256 + 256; ++k) s += xl[k] * Ww[o * 2048 + k];
  part[t] = s;
  __syncthreads();
  if (t < 32) {
    float w = 0.f;
    #pragma unroll
    for (int q = 0; q < 8; ++q) w += part[t + 32 * q];
    w += bw[t];
    comb[32 + t] = fmaxf(w, 0.f);
    float d = bd[t];
    for (int k = 0; k < 64; ++k) d += h3last[b * 64 + k] * Wd[t * 64 + k];
    comb[t] = fmaxf(d, 0.f);
  }
  __syncthreads();
  if (t == 0) {
    float r = bo[0];
    for (int j = 0; j < 64; ++j) r += comb[j] * Wo[j];
    outp[b] = r;
  }
}

static inline int cvt_blocks(long n) {
  long bl = (n / 8 + 255) / 256;
  return (int)(bl > 4096 ? 4096 : bl);
}

extern "C" void kernel_launch(void* const* d_in, const int* in_sizes, int n_in,
                              void* d_out, int out_size, void* d_ws, size_t ws_size,
                              hipStream_t stream) {
  const float* x    = (const float*)d_in[0];
  const float* Wih1 = (const float*)d_in[1];
  const float* Whh1 = (const float*)d_in[2];
  const float* bih1 = (const float*)d_in[3];
  const float* bhh1 = (const float*)d_in[4];
  const float* Wih2 = (const float*)d_in[5];
  const float* Whh2 = (const float*)d_in[6];
  const float* bih2 = (const float*)d_in[7];
  const float* bhh2 = (const float*)d_in[8];
  const float* Wih3 = (const float*)d_in[9];
  const float* Whh3 = (const float*)d_in[10];
  const float* bih3 = (const float*)d_in[11];
  const float* bhh3 = (const float*)d_in[12];
  const float* Wd   = (const float*)d_in[13];
  const float* bd   = (const float*)d_in[14];
  const float* Ww   = (const float*)d_in[15];
  const float* bw   = (const float*)d_in[16];
  const float* Wo   = (const float*)d_in[17];
  const float* bo   = (const float*)d_in[18];

  char* ws = (char*)d_ws;
  // Region A [0, 134217728): x_h (f16); later xg2 f32 @0 and xg3 f32 @+67108864
  // Region B [134217728, 268435456): xg1 f32; later h2 f16
  // Region C [268435456, 285212672): h1 f16
  // Region D: converted Wih weights; Region E: h3last
  f16*   x_h   = (f16*)(ws + 0);
  float* xg1   = (float*)(ws + 134217728);
  f16*   h1    = (f16*)(ws + 268435456);
  f16*   wih1h = (f16*)(ws + 285212672);
  f16*   wih2h = (f16*)(ws + 289406976);
  f16*   wih3h = (f16*)(ws + 289669120);
  float* h3l   = (float*)(ws + 289734656);
  float* xg2   = (float*)(ws + 0);            // alias A (x_h dead after GEMM1)
  f16*   h2    = (f16*)(ws + 134217728);      // alias B (xg1 dead after lstm_l1)
  float* xg3   = (float*)(ws + 67108864);     // alias A upper half (no overlap w/ xg2)

  cvt_f32_f16<<<cvt_blocks(67108864), 256, 0, stream>>>(x, x_h, 67108864L);
  cvt_f32_f16<<<cvt_blocks(2097152), 256, 0, stream>>>(Wih1, wih1h, 2097152L);
  cvt_f32_f16<<<cvt_blocks(131072), 256, 0, stream>>>(Wih2, wih2h, 131072L);
  cvt_f32_f16<<<cvt_blocks(32768), 256, 0, stream>>>(Wih3, wih3h, 32768L);

  gemm_bias<2048><<<dim3(256, 8), 256, 0, stream>>>(x_h, wih1h, bih1, bhh1, xg1, 1024);
  lstm_l1<<<64, 512, 0, stream>>>(xg1, Whh1, h1);
  gemm_bias<256><<<dim3(256, 4), 256, 0, stream>>>(h1, wih2h, bih2, bhh2, xg2, 512);
  lstm_l2<<<64, 512, 0, stream>>>(xg2, Whh2, h2);
  gemm_bias<128><<<dim3(256, 2), 256, 0, stream>>>(h2, wih3h, bih3, bhh3, xg3, 256);
  lstm_l3<<<64, 256, 0, stream>>>(xg3, Whh3, h3l);
  head_kernel<<<64, 256, 0, stream>>>(x, h3l, Wd, bd, Ww, bw, Wo, bo, (float*)d_out);
}

// Round 2
// 2307.650 us; speedup vs baseline: 1.1806x; 1.1806x over previous
//
#include <hip/hip_runtime.h>

typedef _Float16 f16;
typedef _Float16 f16x2 __attribute__((ext_vector_type(2)));
typedef _Float16 f16x8 __attribute__((ext_vector_type(8)));
typedef float    f32x4 __attribute__((ext_vector_type(4)));

__device__ __forceinline__ f16x2 as_h2(unsigned int u) {
  union { unsigned int u; f16x2 h; } c; c.u = u; return c.h;
}
__device__ __forceinline__ unsigned int pack2(float x, float y) {
  union { f16x2 h; unsigned int u; } c; c.h = f16x2{(f16)x, (f16)y}; return c.u;
}
__device__ __forceinline__ float dot2f(unsigned int w, unsigned int h, float acc) {
#if __has_builtin(__builtin_amdgcn_fdot2)
  return __builtin_amdgcn_fdot2(as_h2(w), as_h2(h), acc, false);
#else
  f16x2 a = as_h2(w), b = as_h2(h);
  return acc + (float)a.x * (float)b.x + (float)a.y * (float)b.y;
#endif
}
__device__ __forceinline__ float sigmoidf_(float x) { return 1.f / (1.f + __expf(-x)); }
__device__ __forceinline__ float tanhf_(float x) { float e = __expf(2.f * x); return 1.f - 2.f / (e + 1.f); }

#define GLDS(gsrc, ldst) __builtin_amdgcn_global_load_lds( \
    (const __attribute__((address_space(1))) void*)(gsrc), \
    (__attribute__((address_space(3))) void*)(ldst), 16, 0, 0)

// ---------------- fp32 -> fp16 conversion ----------------
__global__ void cvt_f32_f16(const float* __restrict__ in, f16* __restrict__ out, long n) {
  long i = ((long)blockIdx.x * blockDim.x + threadIdx.x) * 8;
  long stride = (long)gridDim.x * blockDim.x * 8;
  for (; i < n; i += stride) {
    float4 a = *(const float4*)(in + i);
    float4 b = *(const float4*)(in + i + 4);
    f16x8 h = {(f16)a.x, (f16)a.y, (f16)a.z, (f16)a.w,
               (f16)b.x, (f16)b.y, (f16)b.z, (f16)b.w};
    *(f16x8*)(out + i) = h;
  }
}

// ---------------- MFMA GEMM: out[M,N] = A[M,K] @ W[N,K]^T + bias1[N]+bias2[N] ----------------
template<int K>
__global__ __launch_bounds__(256) void gemm_bias(const f16* __restrict__ A,
                                                 const f16* __restrict__ W,
                                                 const float* __restrict__ bias1,
                                                 const float* __restrict__ bias2,
                                                 float* __restrict__ out, int N) {
  constexpr int BK = 32;
  __shared__ f16 As[2][128 * BK];
  __shared__ f16 Bs[2][128 * BK];
  const int tid = threadIdx.x;
  const int wid = tid >> 6, lane = tid & 63;
  const int m0 = blockIdx.x * 128, n0 = blockIdx.y * 128;
  const int wr = (wid >> 1) * 64, wc = (wid & 1) * 64;
  const int r = lane & 15, kg = lane >> 4;

  f32x4 acc[4][4];
  #pragma unroll
  for (int i = 0; i < 4; ++i)
    #pragma unroll
    for (int j = 0; j < 4; ++j) acc[i][j] = f32x4{0.f, 0.f, 0.f, 0.f};

  auto stage = [&](int buf, int k0) {
    #pragma unroll
    for (int i = 0; i < 2; ++i) {
      int c = tid + 256 * i;                       // chunk: 16B = 8 halves
      const f16* asrc = A + (long)(m0 + (c >> 2)) * K + k0 + (c & 3) * 8;
      GLDS(asrc, &As[buf][(64 * wid + 256 * i) * 8]);
      const f16* wsrc = W + (long)(n0 + (c >> 2)) * K + k0 + (c & 3) * 8;
      GLDS(wsrc, &Bs[buf][(64 * wid + 256 * i) * 8]);
    }
  };

  stage(0, 0);
  for (int kt = 0; kt < K / BK; ++kt) {
    __syncthreads();
    if (kt + 1 < K / BK) stage((kt + 1) & 1, (kt + 1) * BK);
    const f16* Ab = As[kt & 1];
    const f16* Bb = Bs[kt & 1];
    f16x8 af[4], bf[4];
    #pragma unroll
    for (int f = 0; f < 4; ++f) {
      af[f] = *(const f16x8*)&Ab[(wr + f * 16 + r) * BK + kg * 8];
      bf[f] = *(const f16x8*)&Bb[(wc + f * 16 + r) * BK + kg * 8];
    }
    #pragma unroll
    for (int mf = 0; mf < 4; ++mf)
      #pragma unroll
      for (int nf = 0; nf < 4; ++nf)
        acc[mf][nf] = __builtin_amdgcn_mfma_f32_16x16x32_f16(af[mf], bf[nf], acc[mf][nf], 0, 0, 0);
  }

  #pragma unroll
  for (int nf = 0; nf < 4; ++nf) {
    int n = n0 + wc + nf * 16 + r;
    float bsum = bias1[n] + bias2[n];
    #pragma unroll
    for (int mf = 0; mf < 4; ++mf) {
      #pragma unroll
      for (int q = 0; q < 4; ++q) {
        int m = m0 + wr + mf * 16 + kg * 4 + q;
        out[(long)m * N + n] = acc[mf][nf][q] + bsum;
      }
    }
  }
}

// ---------------- LSTM layer 1: H=256, gates=1024 ----------------
// Whh f16: k<184 in VGPRs (92 uint pairs per gate, 2 gates/thread = 184 VGPRs),
// k>=184 in LDS (18 units x 4 halves). __launch_bounds__(512,2) -> VGPR cap 256, no spill.
__global__ __launch_bounds__(512, 2) void lstm_l1(const float* __restrict__ xg,   // (64,512,1024) f32
                                                  const float* __restrict__ Whh,  // (1024,256) f32
                                                  f16* __restrict__ hout) {       // (64,512,256) f16
  __shared__ uint2 wtail[18][1024];   // 147456 B: unit u covers k=184+4u..+3
  __shared__ uint4 hbuf[32];          // 256 halves of h
  __shared__ float gact[1024];
  const int b = blockIdx.x;
  const int t = threadIdx.x;
  const int g0 = t, g1 = t + 512;

  unsigned int w0[92], w1[92];        // pairs (2p,2p+1), k<184
  #pragma unroll
  for (int p = 0; p < 92; ++p) {
    float2 f0 = *(const float2*)&Whh[g0 * 256 + 2 * p];
    float2 f1 = *(const float2*)&Whh[g1 * 256 + 2 * p];
    w0[p] = pack2(f0.x, f0.y);
    w1[p] = pack2(f1.x, f1.y);
  }
  #pragma unroll
  for (int u = 0; u < 18; ++u) {
    float4 f0 = *(const float4*)&Whh[g0 * 256 + 184 + 4 * u];
    wtail[u][g0] = make_uint2(pack2(f0.x, f0.y), pack2(f0.z, f0.w));
    float4 f1 = *(const float4*)&Whh[g1 * 256 + 184 + 4 * u];
    wtail[u][g1] = make_uint2(pack2(f1.x, f1.y), pack2(f1.z, f1.w));
  }
  if (t < 32) hbuf[t] = make_uint4(0, 0, 0, 0);
  float c = 0.f;                      // valid for t<256
  __syncthreads();

  const bool g1_sig = (t >= 256);
  const long rowbase = (long)b * 512;
  float a0 = xg[rowbase * 1024 + g0];
  float a1 = xg[rowbase * 1024 + g1];
  for (int ts = 0; ts < 512; ++ts) {
    const long base = rowbase + ts;
    const long nb = rowbase + (ts < 511 ? ts + 1 : 511);
    float a0n = xg[nb * 1024 + g0];            // prefetch next step
    float a1n = xg[nb * 1024 + g1];
    float s0 = 0.f, s1 = 0.f;                  // secondary accumulators (chain split)
    #pragma unroll
    for (int i = 0; i < 23; ++i) {
      uint4 hv = hbuf[i];
      if (i & 1) {
        s0 = dot2f(w0[4 * i + 0], hv.x, s0); s0 = dot2f(w0[4 * i + 1], hv.y, s0);
        s0 = dot2f(w0[4 * i + 2], hv.z, s0); s0 = dot2f(w0[4 * i + 3], hv.w, s0);
        s1 = dot2f(w1[4 * i + 0], hv.x, s1); s1 = dot2f(w1[4 * i + 1], hv.y, s1);
        s1 = dot2f(w1[4 * i + 2], hv.z, s1); s1 = dot2f(w1[4 * i + 3], hv.w, s1);
      } else {
        a0 = dot2f(w0[4 * i + 0], hv.x, a0); a0 = dot2f(w0[4 * i + 1], hv.y, a0);
        a0 = dot2f(w0[4 * i + 2], hv.z, a0); a0 = dot2f(w0[4 * i + 3], hv.w, a0);
        a1 = dot2f(w1[4 * i + 0], hv.x, a1); a1 = dot2f(w1[4 * i + 1], hv.y, a1);
        a1 = dot2f(w1[4 * i + 2], hv.z, a1); a1 = dot2f(w1[4 * i + 3], hv.w, a1);
      }
    }
    #pragma unroll
    for (int j = 0; j < 9; ++j) {
      uint4 hv = hbuf[23 + j];
      uint2 wa0 = wtail[2 * j][g0], wb0 = wtail[2 * j + 1][g0];
      uint2 wa1 = wtail[2 * j][g1], wb1 = wtail[2 * j + 1][g1];
      if (j & 1) {
        s0 = dot2f(wa0.x, hv.x, s0); s0 = dot2f(wa0.y, hv.y, s0);
        s0 = dot2f(wb0.x, hv.z, s0); s0 = dot2f(wb0.y, hv.w, s0);
        s1 = dot2f(wa1.x, hv.x, s1); s1 = dot2f(wa1.y, hv.y, s1);
        s1 = dot2f(wb1.x, hv.z, s1); s1 = dot2f(wb1.y, hv.w, s1);
      } else {
        a0 = dot2f(wa0.x, hv.x, a0); a0 = dot2f(wa0.y, hv.y, a0);
        a0 = dot2f(wb0.x, hv.z, a0); a0 = dot2f(wb0.y, hv.w, a0);
        a1 = dot2f(wa1.x, hv.x, a1); a1 = dot2f(wa1.y, hv.y, a1);
        a1 = dot2f(wb1.x, hv.z, a1); a1 = dot2f(wb1.y, hv.w, a1);
      }
    }
    a0 += s0; a1 += s1;
    gact[g0] = sigmoidf_(a0);
    gact[g1] = g1_sig ? sigmoidf_(a1) : tanhf_(a1);
    __syncthreads();
    if (t < 256) {
      float i_ = gact[t], f_ = gact[256 + t], gg = gact[512 + t], o_ = gact[768 + t];
      c = f_ * c + i_ * gg;
      float hn = o_ * tanhf_(c);
      reinterpret_cast<f16*>(hbuf)[t] = (f16)hn;
      hout[base * 256 + t] = (f16)hn;
    }
    __syncthreads();
    a0 = a0n; a1 = a1n;
  }
}

// ---------------- LSTM layer 2: H=128, gates=512. Whh fully in VGPRs (64 uints/thread) ----------------
__global__ __launch_bounds__(512) void lstm_l2(const float* __restrict__ xg,   // (64,512,512) f32
                                               const float* __restrict__ Whh,  // (512,128) f32
                                               f16* __restrict__ hout) {       // (64,512,128) f16
  __shared__ uint4 hbuf[16];          // 128 halves
  __shared__ float gact[512];
  const int b = blockIdx.x, t = threadIdx.x;
  unsigned int w[64];
  #pragma unroll
  for (int p = 0; p < 64; ++p) {
    float2 f = *(const float2*)&Whh[t * 128 + 2 * p];
    w[p] = pack2(f.x, f.y);
  }
  if (t < 16) hbuf[t] = make_uint4(0, 0, 0, 0);
  float c = 0.f;
  __syncthreads();
  const int type = t >> 7;            // 0:i 1:f 2:g 3:o
  const long rowbase = (long)b * 512;
  float a = xg[rowbase * 512 + t];
  for (int ts = 0; ts < 512; ++ts) {
    const long base = rowbase + ts;
    const long nb = rowbase + (ts < 511 ? ts + 1 : 511);
    float an = xg[nb * 512 + t];
    float s = 0.f;
    #pragma unroll
    for (int i = 0; i < 16; ++i) {
      uint4 hv = hbuf[i];
      if (i & 1) {
        s = dot2f(w[4 * i + 0], hv.x, s); s = dot2f(w[4 * i + 1], hv.y, s);
        s = dot2f(w[4 * i + 2], hv.z, s); s = dot2f(w[4 * i + 3], hv.w, s);
      } else {
        a = dot2f(w[4 * i + 0], hv.x, a); a = dot2f(w[4 * i + 1], hv.y, a);
        a = dot2f(w[4 * i + 2], hv.z, a); a = dot2f(w[4 * i + 3], hv.w, a);
      }
    }
    a += s;
    gact[t] = (type == 2) ? tanhf_(a) : sigmoidf_(a);
    __syncthreads();
    if (t < 128) {
      float i_ = gact[t], f_ = gact[128 + t], gg = gact[256 + t], o_ = gact[384 + t];
      c = f_ * c + i_ * gg;
      float hn = o_ * tanhf_(c);
      reinterpret_cast<f16*>(hbuf)[t] = (f16)hn;
      hout[base * 128 + t] = (f16)hn;
    }
    __syncthreads();
    a = an;
  }
}

// ---------------- LSTM layer 3: H=64, gates=256. Whh in VGPRs (32 uints/thread) ----------------
__global__ __launch_bounds__(256) void lstm_l3(const float* __restrict__ xg,    // (64,512,256) f32
                                               const float* __restrict__ Whh,   // (256,64) f32
                                               float* __restrict__ h3last) {    // (64,64) f32
  __shared__ uint4 hbuf[8];           // 64 halves
  __shared__ float gact[256];
  const int b = blockIdx.x, t = threadIdx.x;
  unsigned int w[32];
  #pragma unroll
  for (int p = 0; p < 32; ++p) {
    float2 f = *(const float2*)&Whh[t * 64 + 2 * p];
    w[p] = pack2(f.x, f.y);
  }
  if (t < 8) hbuf[t] = make_uint4(0, 0, 0, 0);
  float c = 0.f;
  __syncthreads();
  const int type = t >> 6;
  const long rowbase = (long)b * 512;
  float a = xg[rowbase * 256 + t];
  for (int ts = 0; ts < 512; ++ts) {
    const long nb = rowbase + (ts < 511 ? ts + 1 : 511);
    float an = xg[nb * 256 + t];
    float s = 0.f;
    #pragma unroll
    for (int i = 0; i < 8; ++i) {
      uint4 hv = hbuf[i];
      if (i & 1) {
        s = dot2f(w[4 * i + 0], hv.x, s); s = dot2f(w[4 * i + 1], hv.y, s);
        s = dot2f(w[4 * i + 2], hv.z, s); s = dot2f(w[4 * i + 3], hv.w, s);
      } else {
        a = dot2f(w[4 * i + 0], hv.x, a); a = dot2f(w[4 * i + 1], hv.y, a);
        a = dot2f(w[4 * i + 2], hv.z, a); a = dot2f(w[4 * i + 3], hv.w, a);
      }
    }
    a += s;
    gact[t] = (type == 2) ? tanhf_(a) : sigmoidf_(a);
    __syncthreads();
    if (t < 64) {
      float i_ = gact[t], f_ = gact[64 + t], gg = gact[128 + t], o_ = gact[192 + t];
      c = f_ * c + i_ * gg;
      float hn = o_ * tanhf_(c);
      reinterpret_cast<f16*>(hbuf)[t] = (f16)hn;
      if (ts == 511) h3last[b * 64 + t] = hn;
    }
    __syncthreads();
    a = an;
  }
}

// ---------------- head: deep/wide + final linear ----------------
__global__ __launch_bounds__(256) void head_kernel(const float* __restrict__ x,       // (64,512,2048)
                                                   const float* __restrict__ h3last,  // (64,64)
                                                   const float* __restrict__ Wd, const float* __restrict__ bd,
                                                   const float* __restrict__ Ww, const float* __restrict__ bw,
                                                   const float* __restrict__ Wo, const float* __restrict__ bo,
                                                   float* __restrict__ outp) {
  __shared__ float part[256];
  __shared__ float comb[64];
  const int b = blockIdx.x, t = threadIdx.x;
  const int o = t & 31, seg = t >> 5;
  const float* xl = x + ((long)b * 512 + 511) * 2048;
  float s = 0.f;
  for (int k = seg * 256; k < seg * 256 + 256; ++k) s += xl[k] * Ww[o * 2048 + k];
  part[t] = s;
  __syncthreads();
  if (t < 32) {
    float w = 0.f;
    #pragma unroll
    for (int q = 0; q < 8; ++q) w += part[t + 32 * q];
    w += bw[t];
    comb[32 + t] = fmaxf(w, 0.f);
    float d = bd[t];
    for (int k = 0; k < 64; ++k) d += h3last[b * 64 + k] * Wd[t * 64 + k];
    comb[t] = fmaxf(d, 0.f);
  }
  __syncthreads();
  if (t == 0) {
    float r = bo[0];
    for (int j = 0; j < 64; ++j) r += comb[j] * Wo[j];
    outp[b] = r;
  }
}

static inline int cvt_blocks(long n) {
  long bl = (n / 8 + 255) / 256;
  return (int)(bl > 4096 ? 4096 : bl);
}

extern "C" void kernel_launch(void* const* d_in, const int* in_sizes, int n_in,
                              void* d_out, int out_size, void* d_ws, size_t ws_size,
                              hipStream_t stream) {
  const float* x    = (const float*)d_in[0];
  const float* Wih1 = (const float*)d_in[1];
  const float* Whh1 = (const float*)d_in[2];
  const float* bih1 = (const float*)d_in[3];
  const float* bhh1 = (const float*)d_in[4];
  const float* Wih2 = (const float*)d_in[5];
  const float* Whh2 = (const float*)d_in[6];
  const float* bih2 = (const float*)d_in[7];
  const float* bhh2 = (const float*)d_in[8];
  const float* Wih3 = (const float*)d_in[9];
  const float* Whh3 = (const float*)d_in[10];
  const float* bih3 = (const float*)d_in[11];
  const float* bhh3 = (const float*)d_in[12];
  const float* Wd   = (const float*)d_in[13];
  const float* bd   = (const float*)d_in[14];
  const float* Ww   = (const float*)d_in[15];
  const float* bw   = (const float*)d_in[16];
  const float* Wo   = (const float*)d_in[17];
  const float* bo   = (const float*)d_in[18];

  char* ws = (char*)d_ws;
  f16*   x_h   = (f16*)(ws + 0);
  float* xg1   = (float*)(ws + 134217728);
  f16*   h1    = (f16*)(ws + 268435456);
  f16*   wih1h = (f16*)(ws + 285212672);
  f16*   wih2h = (f16*)(ws + 289406976);
  f16*   wih3h = (f16*)(ws + 289669120);
  float* h3l   = (float*)(ws + 289734656);
  float* xg2   = (float*)(ws + 0);            // alias A (x_h dead after GEMM1)
  f16*   h2    = (f16*)(ws + 134217728);      // alias B (xg1 dead after lstm_l1)
  float* xg3   = (float*)(ws + 67108864);     // alias A upper half (no overlap w/ xg2)

  cvt_f32_f16<<<cvt_blocks(67108864), 256, 0, stream>>>(x, x_h, 67108864L);
  cvt_f32_f16<<<cvt_blocks(2097152), 256, 0, stream>>>(Wih1, wih1h, 2097152L);
  cvt_f32_f16<<<cvt_blocks(131072), 256, 0, stream>>>(Wih2, wih2h, 131072L);
  cvt_f32_f16<<<cvt_blocks(32768), 256, 0, stream>>>(Wih3, wih3h, 32768L);

  gemm_bias<2048><<<dim3(256, 8), 256, 0, stream>>>(x_h, wih1h, bih1, bhh1, xg1, 1024);
  lstm_l1<<<64, 512, 0, stream>>>(xg1, Whh1, h1);
  gemm_bias<256><<<dim3(256, 4), 256, 0, stream>>>(h1, wih2h, bih2, bhh2, xg2, 512);
  lstm_l2<<<64, 512, 0, stream>>>(xg2, Whh2, h2);
  gemm_bias<128><<<dim3(256, 2), 256, 0, stream>>>(h2, wih3h, bih3, bhh3, xg3, 256);
  lstm_l3<<<64, 256, 0, stream>>>(xg3, Whh3, h3l);
  head_kernel<<<64, 256, 0, stream>>>(x, h3l, Wd, bd, Ww, bw, Wo, bo, (float*)d_out);
}